// Round 4
// baseline (231.232 us; speedup 1.0000x reference)
//
#include <hip/hip_runtime.h>
#include <hip/hip_bf16.h>

#define H_ 96
#define W_ 96
#define HW_ 9216
#define C_ 256
#define B_ 2
#define KO_ 27
#define EPS_ 1e-5f

typedef unsigned short u16;
typedef unsigned short ushort4v __attribute__((ext_vector_type(4)));
typedef unsigned short ushort8 __attribute__((ext_vector_type(8)));
typedef short short8v __attribute__((ext_vector_type(8)));
typedef float float4v __attribute__((ext_vector_type(4)));

__device__ __forceinline__ float b2f(u16 u) {
    return __uint_as_float(((unsigned int)u) << 16);
}
__device__ __forceinline__ u16 f2b(float f) {
    __hip_bfloat16 h = __float2bfloat16(f);
    union { __hip_bfloat16 h; u16 u; } cv; cv.h = h; return cv.u;
}
__device__ __forceinline__ unsigned int pack2(float a, float b) {
    union { __hip_bfloat162 h; unsigned int u; } cv;
    cv.h = __float22bfloat162_rn(make_float2(a, b));
    return cv.u;
}

// ---------------- kernel 1: weight repacks + BN fold -------
__global__ __launch_bounds__(256) void prep_w_kernel(
    const float* __restrict__ w_conv, const float* __restrict__ w_off,
    const float* __restrict__ b_conv,
    const float* __restrict__ gamma, const float* __restrict__ beta,
    const float* __restrict__ rmean, const float* __restrict__ rvar,
    float* __restrict__ AB, u16* __restrict__ WQ, u16* __restrict__ WO)
{
    if (blockIdx.x == 0) {
        int o = threadIdx.x;
        float sc = gamma[o] * rsqrtf(rvar[o] + EPS_);
        AB[o] = sc;
        AB[256 + o] = beta[o] + (b_conv[o] - rmean[o]) * sc;
    }
    if (blockIdx.x < 2304) {
        int idx = blockIdx.x * 256 + threadIdx.x;   // 589824 total
        int ch = idx >> 13;          // chunk = k*8 + c/32
        int o  = (idx >> 5) & 255;
        int cp = idx & 31;
        int c  = ((ch & 7) << 5) + cp;
        int k  = ch >> 3;
        WQ[idx] = f2b(w_conv[(o * C_ + c) * 9 + k]);
    } else {
        int j = (blockIdx.x - 2304) * 256 + threadIdx.x;  // 73728 total
        int ch = j >> 10;
        int o  = (j >> 5) & 31;
        int cp = j & 31;
        int c  = ((ch & 7) << 5) + cp;
        int k  = ch >> 3;
        WO[j] = (o < KO_) ? f2b(w_off[(o * C_ + c) * 9 + k]) : (u16)0;
    }
}

// ---------------- kernel 2: x NCHW f32 -> NHWC bf16 ----------------
__global__ __launch_bounds__(256) void xt_kernel(const float* __restrict__ x,
                                                 u16* __restrict__ XT)
{
    __shared__ u16 ls[32][100];
    int h  = blockIdx.x;
    int cg = blockIdx.y & 7;
    int b  = blockIdx.y >> 3;
    int c0 = cg * 32;
    for (int e = threadIdx.x; e < 32 * W_; e += 256) {
        int ci = e / W_, w = e % W_;
        ls[ci][w] = f2b(x[((b * C_ + c0 + ci) * H_ + h) * W_ + w]);
    }
    __syncthreads();
    for (int e = threadIdx.x; e < 32 * W_; e += 256) {
        int w = e >> 5, ci = e & 31;
        XT[((b * H_ + h) * W_ + w) * C_ + c0 + ci] = ls[ci][w];
    }
}

// ---------------- kernel 3: offset conv MFMA GEMM, K-split 2 ----------------
// grid (144 px-tiles, ks=2, b=2). Writes fp32 partials P[(ks*2+b)*32+o][pix].
__global__ __launch_bounds__(256, 4) void offmfma_kernel(
    const u16* __restrict__ XT, const u16* __restrict__ WO,
    float* __restrict__ P)
{
    const int tid = threadIdx.x;
    const int ks = blockIdx.y;
    const int b  = blockIdx.z;
    const int ht = blockIdx.x / 6, wt = blockIdx.x % 6;
    const int h0 = ht * 4, w0 = wt * 16;

    const int wave = tid >> 6;
    const int lane = tid & 63;
    const int quad = lane >> 4;
    const int l15  = lane & 15;

    const int ph = h0 + wave;
    const int pw = w0 + l15;
    const int s0 = ks * 36;

    float4v acc[2];
    acc[0] = float4v{0.f, 0.f, 0.f, 0.f};
    acc[1] = float4v{0.f, 0.f, 0.f, 0.f};

    int basec; bool vld;
    auto compute_base = [&](int k) {
        int py  = ph + (k / 3) - 1;
        int pxl = pw + (k % 3) - 1;
        vld = ((unsigned)py < (unsigned)H_) && ((unsigned)pxl < (unsigned)W_);
        int pyc = min(max(py, 0), H_ - 1);
        int pxc = min(max(pxl, 0), W_ - 1);
        basec = ((b * H_ + pyc) * W_ + pxc) * C_ + quad * 8;
    };
    auto g_load = [&](int ch) -> ushort8 {
        ushort8 v = *(const ushort8*)(XT + basec + (ch & 7) * 32);
#pragma unroll
        for (int j = 0; j < 8; j++) v[j] = vld ? v[j] : (u16)0;
        return v;
    };

    ushort8 bq0, bq1, bq2, bq3;
    short8v aq[4][2];
    auto load_w = [&](int ch, short8v A[2]) {
        const u16* p = WO + ch * 1024 + l15 * 32 + quad * 8;
        A[0] = *(const short8v*)(p);
        A[1] = *(const short8v*)(p + 512);
    };

    compute_base(s0 >> 3);
    bq0 = g_load(s0); bq1 = g_load(s0 + 1); bq2 = g_load(s0 + 2); bq3 = g_load(s0 + 3);
    load_w(s0, aq[0]); load_w(s0 + 1, aq[1]); load_w(s0 + 2, aq[2]); load_w(s0 + 3, aq[3]);

    auto step = [&](int ch, ushort8& slot, short8v A[2]) {
        int p = ch + 4;
        if (p < s0 + 36 && (p & 7) == 0) compute_base(p >> 3);
        ushort8 bv = slot;
        short8v a0 = A[0], a1 = A[1];
        if (p < s0 + 36) { slot = g_load(p); load_w(p, A); }
        union { ushort8 u; short8v s; } cb; cb.u = bv;
        acc[0] = __builtin_amdgcn_mfma_f32_16x16x32_bf16(a0, cb.s, acc[0], 0, 0, 0);
        acc[1] = __builtin_amdgcn_mfma_f32_16x16x32_bf16(a1, cb.s, acc[1], 0, 0, 0);
    };

    for (int it = s0; it < s0 + 36; it += 4) {
        step(it,     bq0, aq[0]);
        step(it + 1, bq1, aq[1]);
        step(it + 2, bq2, aq[2]);
        step(it + 3, bq3, aq[3]);
    }

    const int pix = ph * W_ + pw;
    const int pb = (ks * 2 + b) * 32;
#pragma unroll
    for (int mt = 0; mt < 2; mt++) {
#pragma unroll
        for (int r = 0; r < 4; r++) {
            int o = mt * 16 + quad * 4 + r;
            P[(pb + o) * HW_ + pix] = acc[mt][r];
        }
    }
}

// ---------------- kernel 4: combine partials -> DY/DX/MASK ----------------
__global__ __launch_bounds__(256) void combine_kernel(const float* __restrict__ P,
    const float* __restrict__ b_off,
    float* __restrict__ DY, float* __restrict__ DX, float* __restrict__ MK)
{
    int idx = blockIdx.x * 256 + threadIdx.x;   // 2*27*9216 = 497664
    int bb = idx / (KO_ * HW_);
    int r  = idx % (KO_ * HW_);
    int o  = r / HW_;
    int pix = r % HW_;
    float v = P[(bb * 32 + o) * HW_ + pix] + P[((2 + bb) * 32 + o) * HW_ + pix]
            + b_off[o];
    if (o < 18) {
        float* dst = (o & 1) ? DX : DY;
        dst[(bb * 9 + (o >> 1)) * HW_ + pix] = v;
    } else {
        MK[(bb * 9 + (o - 18)) * HW_ + pix] = 1.f / (1.f + expf(-v));
    }
}

// ---------------- kernel 5: deformable GEMM v3 ----------------
// Block: 256o x 16px, chunk = 64ch (36 chunks), 4 waves each 64o x 16px.
// Lerp shared across all 256 o; XOR-swizzled LDS (conflict-free b128).
__global__ __launch_bounds__(256, 4) void deform_kernel(
    const float* __restrict__ x, const u16* __restrict__ XT,
    const u16* __restrict__ WQ,
    const float* __restrict__ DY, const float* __restrict__ DX,
    const float* __restrict__ MK, const float* __restrict__ AB,
    float* __restrict__ out)
{
    __shared__ __align__(16) u16 s_s[2][16][64];

    const int tid = threadIdx.x;
    const int b  = blockIdx.y;
    const int h  = blockIdx.x / 6;
    const int w0 = (blockIdx.x % 6) * 16;

    // fill mapping: 16 threads per pixel, 4 channels each
    const int px_f = tid >> 4;     // 0..15
    const int sub  = tid & 15;     // 4-ch subgroup
    const int pw_f = w0 + px_f;
    const int pix_f = h * W_ + pw_f;
    // swizzled store column (ch units): granule (sub>>1) ^ (px&7), half sub&1
    const int col_st = (((sub >> 1) ^ (px_f & 7)) << 3) + ((sub & 1) << 2);

    // gemm mapping
    const int wave = tid >> 6;
    const int lane = tid & 63;
    const int quad = lane >> 4;
    const int l15  = lane & 15;
    const int wo = wave * 64;

    float4v acc[4];
#pragma unroll
    for (int i = 0; i < 4; i++) acc[i] = float4v{0.f, 0.f, 0.f, 0.f};

    const float* DYb = DY + b * 9 * HW_ + pix_f;
    const float* DXb = DX + b * 9 * HW_ + pix_f;
    const float* MKb = MK + b * 9 * HW_ + pix_f;

    int a00, a01, a10, a11;
    float fw0, fw1, fw2, fw3;
    float nk_dy, nk_dx, nk_m;

    auto make_params = [&](int k, float dyv, float dxv, float m) {
        float py  = (float)(h + (k / 3) - 1) + dyv;
        float pxx = (float)(pw_f + (k % 3) - 1) + dxv;
        float y0f = floorf(py), x0f = floorf(pxx);
        float ly = py - y0f, lx = pxx - x0f;
        int y0 = (int)y0f, x0i = (int)x0f;
        int y1 = y0 + 1, x1 = x0i + 1;
        bool vy0 = (unsigned)y0 < (unsigned)H_;
        bool vy1 = (unsigned)y1 < (unsigned)H_;
        bool vx0 = (unsigned)x0i < (unsigned)W_;
        bool vx1 = (unsigned)x1 < (unsigned)W_;
        fw0 = (vy0 && vx0) ? (1.f - ly) * (1.f - lx) * m : 0.f;
        fw1 = (vy0 && vx1) ? (1.f - ly) * lx * m : 0.f;
        fw2 = (vy1 && vx0) ? ly * (1.f - lx) * m : 0.f;
        fw3 = (vy1 && vx1) ? ly * lx * m : 0.f;
        int y0c = min(max(y0, 0), H_ - 1), y1c = min(max(y1, 0), H_ - 1);
        int x0c = min(max(x0i, 0), W_ - 1), x1c = min(max(x1, 0), W_ - 1);
        a00 = ((b * H_ + y0c) * W_ + x0c) * C_;
        a01 = ((b * H_ + y0c) * W_ + x1c) * C_;
        a10 = ((b * H_ + y1c) * W_ + x0c) * C_;
        a11 = ((b * H_ + y1c) * W_ + x1c) * C_;
    };

    ushort4v g00, g01, g10, g11;
    auto load_g = [&](int ch) {
        const int co = ((ch & 3) << 6) + (sub << 2);
        g00 = *(const ushort4v*)(XT + a00 + co);
        g01 = *(const ushort4v*)(XT + a01 + co);
        g10 = *(const ushort4v*)(XT + a10 + co);
        g11 = *(const ushort4v*)(XT + a11 + co);
    };
    auto lerp_store = [&](int buf) {
        float v[4];
#pragma unroll
        for (int j = 0; j < 4; j++)
            v[j] = fw0 * b2f(g00[j]) + fw1 * b2f(g01[j])
                 + fw2 * b2f(g10[j]) + fw3 * b2f(g11[j]);
        uint2 sv;
        sv.x = pack2(v[0], v[1]);
        sv.y = pack2(v[2], v[3]);
        *(uint2*)&s_s[buf][px_f][col_st] = sv;
    };

    short8v a_cur[2][4], a_nxt[2][4];
    auto load_a = [&](int ch, short8v A[2][4]) {
        const int tap = ch >> 2;
        const int cg  = (ch & 3) << 1;
        const u16* p = WQ + ((tap * 8 + cg) * 256 + wo + l15) * 32 + quad * 8;
#pragma unroll
        for (int ksx = 0; ksx < 2; ++ksx)
#pragma unroll
            for (int mt = 0; mt < 4; ++mt)
                A[ksx][mt] = *(const short8v*)(p + ksx * 8192 + mt * 512);
    };

    // ---- prologue ----
    {
        float d0 = DYb[0], e0 = DXb[0], m0 = MKb[0];
        make_params(0, d0, e0, m0);
        nk_dy = DYb[HW_]; nk_dx = DXb[HW_]; nk_m = MKb[HW_];
    }
    load_g(0);
    load_a(0, a_cur);
    lerp_store(0);
    __syncthreads();

    int buf = 0;
    for (int ch = 0; ch < 36; ++ch) {
        const int nx = ch + 1;
        if (nx < 36) {
            if ((nx & 3) == 0) {
                const int t = nx >> 2;
                make_params(t, nk_dy, nk_dx, nk_m);
                if (t < 8) {
                    nk_dy = DYb[(t + 1) * HW_];
                    nk_dx = DXb[(t + 1) * HW_];
                    nk_m  = MKb[(t + 1) * HW_];
                }
            }
            load_g(nx);
            load_a(nx, a_nxt);
        }
        short8v b0 = *(const short8v*)&s_s[buf][l15][(quad ^ (l15 & 7)) << 3];
        short8v b1 = *(const short8v*)&s_s[buf][l15][((4 + quad) ^ (l15 & 7)) << 3];
#pragma unroll
        for (int mt = 0; mt < 4; ++mt)
            acc[mt] = __builtin_amdgcn_mfma_f32_16x16x32_bf16(
                a_cur[0][mt], b0, acc[mt], 0, 0, 0);
#pragma unroll
        for (int mt = 0; mt < 4; ++mt)
            acc[mt] = __builtin_amdgcn_mfma_f32_16x16x32_bf16(
                a_cur[1][mt], b1, acc[mt], 0, 0, 0);
        if (nx < 36) lerp_store(buf ^ 1);
#pragma unroll
        for (int ksx = 0; ksx < 2; ++ksx)
#pragma unroll
            for (int mt = 0; mt < 4; ++mt)
                a_cur[ksx][mt] = a_nxt[ksx][mt];
        __syncthreads();
        buf ^= 1;
    }

    // ---- epilogue: BN fold + relu + residual ----
    const float* Ao = AB;
    const float* Bo = AB + 256;
    const int pix0 = h * W_ + w0;
#pragma unroll
    for (int mt = 0; mt < 4; mt++) {
#pragma unroll
        for (int r = 0; r < 4; r++) {
            int o = wo + mt * 16 + quad * 4 + r;
            float v = acc[mt][r] * Ao[o] + Bo[o];
            v = fmaxf(v, 0.f);
            int gi = (b * C_ + o) * HW_ + pix0 + l15;
            out[gi] = x[gi] + v;
        }
    }
}

extern "C" void kernel_launch(void* const* d_in, const int* in_sizes, int n_in,
                              void* d_out, int out_size, void* d_ws, size_t ws_size,
                              hipStream_t stream)
{
    (void)in_sizes; (void)n_in; (void)out_size; (void)ws_size;
    const float* x      = (const float*)d_in[0];
    const float* w_off  = (const float*)d_in[1];
    const float* b_off  = (const float*)d_in[2];
    const float* w_conv = (const float*)d_in[3];
    const float* b_conv = (const float*)d_in[4];
    const float* gamma  = (const float*)d_in[5];
    const float* beta   = (const float*)d_in[6];
    const float* rmean  = (const float*)d_in[7];
    const float* rvar   = (const float*)d_in[8];
    float* out = (float*)d_out;

    float* ws = (float*)d_ws;
    float* DY = ws;                            // 165888
    float* DX = DY + 165888;
    float* MK = DX + 165888;
    float* AB = MK + 165888;                   // 512
    float* P  = AB + 512;                      // 2*2*32*9216 = 1179648
    u16* WQ = (u16*)(P + 1179648);             // 589824
    u16* WO = WQ + 589824;                     // 73728
    u16* XT = WO + 73728;                      // 4718592

    prep_w_kernel<<<2592, 256, 0, stream>>>(w_conv, w_off, b_conv, gamma, beta,
                                            rmean, rvar, AB, WQ, WO);
    xt_kernel<<<dim3(96, 16), 256, 0, stream>>>(x, XT);
    offmfma_kernel<<<dim3(144, 2, 2), 256, 0, stream>>>(XT, WO, P);
    combine_kernel<<<1944, 256, 0, stream>>>(P, b_off, DY, DX, MK);
    deform_kernel<<<dim3(576, 2), 256, 0, stream>>>(x, XT, WQ, DY, DX, MK, AB, out);
}

// Round 5
// 201.815 us; speedup vs baseline: 1.1458x; 1.1458x over previous
//
#include <hip/hip_runtime.h>
#include <hip/hip_bf16.h>

#define H_ 96
#define W_ 96
#define HW_ 9216
#define C_ 256
#define B_ 2
#define KO_ 27
#define EPS_ 1e-5f

typedef unsigned short u16;
typedef unsigned short ushort8 __attribute__((ext_vector_type(8)));
typedef short short8v __attribute__((ext_vector_type(8)));
typedef float float4v __attribute__((ext_vector_type(4)));

__device__ __forceinline__ float b2f(u16 u) {
    return __uint_as_float(((unsigned int)u) << 16);
}
__device__ __forceinline__ u16 f2b(float f) {
    __hip_bfloat16 h = __float2bfloat16(f);
    union { __hip_bfloat16 h; u16 u; } cv; cv.h = h; return cv.u;
}
__device__ __forceinline__ unsigned int pack2(float a, float b) {
    union { __hip_bfloat162 h; unsigned int u; } cv;
    cv.h = __float22bfloat162_rn(make_float2(a, b));
    return cv.u;
}

// ---------------- kernel 1: weight repacks + BN fold -------
// WQ[((tap*8+cg)*256+o)*32+cp] = bf16(w_conv[o][c][tap]),  c = cg*32+cp
// WO[(tap*8+cg)*1024 + o*32 + cp] = bf16(w_off[o][c][tap]) (o<27, else 0)
__global__ __launch_bounds__(256) void prep_w_kernel(
    const float* __restrict__ w_conv, const float* __restrict__ w_off,
    const float* __restrict__ b_conv,
    const float* __restrict__ gamma, const float* __restrict__ beta,
    const float* __restrict__ rmean, const float* __restrict__ rvar,
    float* __restrict__ AB, u16* __restrict__ WQ, u16* __restrict__ WO)
{
    if (blockIdx.x == 0) {
        int o = threadIdx.x;
        float sc = gamma[o] * rsqrtf(rvar[o] + EPS_);
        AB[o] = sc;
        AB[256 + o] = beta[o] + (b_conv[o] - rmean[o]) * sc;
    }
    if (blockIdx.x < 2304) {
        int idx = blockIdx.x * 256 + threadIdx.x;   // 589824 total
        int ch = idx >> 13;          // chunk = tap*8 + c/32
        int o  = (idx >> 5) & 255;
        int cp = idx & 31;
        int c  = ((ch & 7) << 5) + cp;
        int k  = ch >> 3;
        WQ[idx] = f2b(w_conv[(o * C_ + c) * 9 + k]);
    } else {
        int j = (blockIdx.x - 2304) * 256 + threadIdx.x;  // 73728 total
        int ch = j >> 10;
        int o  = (j >> 5) & 31;
        int cp = j & 31;
        int c  = ((ch & 7) << 5) + cp;
        int k  = ch >> 3;
        WO[j] = (o < KO_) ? f2b(w_off[(o * C_ + c) * 9 + k]) : (u16)0;
    }
}

// ---------------- kernel 2: x NCHW f32 -> NHWC bf16 ----------------
__global__ __launch_bounds__(256) void xt_kernel(const float* __restrict__ x,
                                                 u16* __restrict__ XT)
{
    __shared__ u16 ls[32][100];
    int h  = blockIdx.x;
    int cg = blockIdx.y & 7;
    int b  = blockIdx.y >> 3;
    int c0 = cg * 32;
    for (int e = threadIdx.x; e < 32 * W_; e += 256) {
        int ci = e / W_, w = e % W_;
        ls[ci][w] = f2b(x[((b * C_ + c0 + ci) * H_ + h) * W_ + w]);
    }
    __syncthreads();
    for (int e = threadIdx.x; e < 32 * W_; e += 256) {
        int w = e >> 5, ci = e & 31;
        XT[((b * H_ + h) * W_ + w) * C_ + c0 + ci] = ls[ci][w];
    }
}

// ---------------- kernel 3: offsets (MFMA, K-split across waves) + lerp -> S --
// Block = 16 px (one row segment). Phase 1: 27x2304 GEMM for these px, waves
// take K quarters, LDS-reduce, sigmoid -> offv in LDS. Phase 2: gather+lerp
// all 2304 K values per px, write bf16 S[b][pix][kk] (kk = tap*256 + c).
__global__ __launch_bounds__(256) void off_lerp_kernel(
    const u16* __restrict__ XT, const u16* __restrict__ WO,
    const float* __restrict__ b_off, u16* __restrict__ S)
{
    __shared__ float red[4][32][16];
    __shared__ float offv[27][16];

    const int tid = threadIdx.x;
    const int b  = blockIdx.y;
    const int p0 = blockIdx.x * 16;
    const int h  = p0 / W_;            // 16 px all on one row
    const int w0 = p0 % W_;

    const int wave = tid >> 6;
    const int lane = tid & 63;
    const int quad = lane >> 4;
    const int l15  = lane & 15;

    // ---- phase 1 ----
    {
        const int pw = w0 + l15;
        float4v acc0 = float4v{0.f,0.f,0.f,0.f};
        float4v acc1 = float4v{0.f,0.f,0.f,0.f};
        int basec = 0; bool vld = true; int curtap = -1;
        auto set_tap = [&](int tap) {
            int py  = h + tap / 3 - 1;
            int pxl = pw + tap % 3 - 1;
            vld = ((unsigned)py < (unsigned)H_) && ((unsigned)pxl < (unsigned)W_);
            int pyc = min(max(py, 0), H_ - 1);
            int pxc = min(max(pxl, 0), W_ - 1);
            basec = ((b * H_ + pyc) * W_ + pxc) * C_ + quad * 8;
        };
        auto bload = [&](int c32) -> ushort8 {
            ushort8 v = *(const ushort8*)(XT + basec + (c32 & 7) * 32);
#pragma unroll
            for (int j = 0; j < 8; j++) v[j] = vld ? v[j] : (u16)0;
            return v;
        };
        const int c0 = wave * 18, c1 = c0 + 18;
        curtap = c0 >> 3;
        set_tap(curtap);
        ushort8 bq = bload(c0);
        short8v wa = *(const short8v*)(WO + c0 * 1024 + l15 * 32 + quad * 8);
        short8v wb = *(const short8v*)(WO + c0 * 1024 + l15 * 32 + quad * 8 + 512);
        for (int i = c0; i < c1; ++i) {
            ushort8 bc = bq;
            short8v wac = wa, wbc = wb;
            int nx = i + 1;
            if (nx < c1) {
                int t = nx >> 3;
                if (t != curtap) { set_tap(t); curtap = t; }
                bq = bload(nx);
                wa = *(const short8v*)(WO + nx * 1024 + l15 * 32 + quad * 8);
                wb = *(const short8v*)(WO + nx * 1024 + l15 * 32 + quad * 8 + 512);
            }
            union { ushort8 u; short8v s; } cb; cb.u = bc;
            acc0 = __builtin_amdgcn_mfma_f32_16x16x32_bf16(wac, cb.s, acc0, 0, 0, 0);
            acc1 = __builtin_amdgcn_mfma_f32_16x16x32_bf16(wbc, cb.s, acc1, 0, 0, 0);
        }
#pragma unroll
        for (int r = 0; r < 4; ++r) {
            red[wave][quad * 4 + r][l15]      = acc0[r];
            red[wave][16 + quad * 4 + r][l15] = acc1[r];
        }
    }
    __syncthreads();
#pragma unroll
    for (int rep = 0; rep < 2; ++rep) {
        int o  = (tid >> 4) + rep * 16;   // 0..31
        int px = tid & 15;
        if (o < KO_) {
            float v = red[0][o][px] + red[1][o][px] + red[2][o][px] + red[3][o][px]
                    + b_off[o];
            offv[o][px] = (o < 18) ? v : 1.f / (1.f + expf(-v));
        }
    }
    __syncthreads();

    // ---- phase 2: gather + lerp -> S ----
    const int px = tid >> 4;      // 0..15
    const int j  = tid & 15;      // ch-lane
    const int pw2 = w0 + px;
    const int pix = h * W_ + pw2;
    u16* srow = S + (size_t)(b * HW_ + pix) * 2304;

    for (int tap = 0; tap < 9; ++tap) {
        float dy = offv[2 * tap][px];
        float dx = offv[2 * tap + 1][px];
        float m  = offv[18 + tap][px];
        float py  = (float)(h + tap / 3 - 1) + dy;
        float pxx = (float)(pw2 + tap % 3 - 1) + dx;
        float y0f = floorf(py), x0f = floorf(pxx);
        float ly = py - y0f, lx = pxx - x0f;
        int y0 = (int)y0f, x0i = (int)x0f;
        int y1 = y0 + 1, x1 = x0i + 1;
        bool vy0 = (unsigned)y0 < (unsigned)H_;
        bool vy1 = (unsigned)y1 < (unsigned)H_;
        bool vx0 = (unsigned)x0i < (unsigned)W_;
        bool vx1 = (unsigned)x1 < (unsigned)W_;
        float fw0 = (vy0 && vx0) ? (1.f - ly) * (1.f - lx) * m : 0.f;
        float fw1 = (vy0 && vx1) ? (1.f - ly) * lx * m : 0.f;
        float fw2 = (vy1 && vx0) ? ly * (1.f - lx) * m : 0.f;
        float fw3 = (vy1 && vx1) ? ly * lx * m : 0.f;
        int y0c = min(max(y0, 0), H_ - 1), y1c = min(max(y1, 0), H_ - 1);
        int x0c = min(max(x0i, 0), W_ - 1), x1c = min(max(x1, 0), W_ - 1);
        int a00 = ((b * H_ + y0c) * W_ + x0c) * C_;
        int a01 = ((b * H_ + y0c) * W_ + x1c) * C_;
        int a10 = ((b * H_ + y1c) * W_ + x0c) * C_;
        int a11 = ((b * H_ + y1c) * W_ + x1c) * C_;
#pragma unroll
        for (int cc = 0; cc < 2; ++cc) {
            int ch = cc * 128 + j * 8;
            ushort8 v00 = *(const ushort8*)(XT + a00 + ch);
            ushort8 v01 = *(const ushort8*)(XT + a01 + ch);
            ushort8 v10 = *(const ushort8*)(XT + a10 + ch);
            ushort8 v11 = *(const ushort8*)(XT + a11 + ch);
            float v[8];
#pragma unroll
            for (int t = 0; t < 8; t++)
                v[t] = fw0 * b2f(v00[t]) + fw1 * b2f(v01[t])
                     + fw2 * b2f(v10[t]) + fw3 * b2f(v11[t]);
            uint4 sv;
            sv.x = pack2(v[0], v[1]);
            sv.y = pack2(v[2], v[3]);
            sv.z = pack2(v[4], v[5]);
            sv.w = pack2(v[6], v[7]);
            *(uint4*)(srow + tap * 256 + ch) = sv;
        }
    }
}

// ---------------- kernel 4: GEMM out = relu(BN(W*S)) + x ----------------
// Block 128o x 64px, K=2304 in 36 chunks of 64. A-frags direct from WQ (L2),
// S staged in XOR-swizzled LDS, S loads 2 chunks ahead, 1 barrier/chunk.
__global__ __launch_bounds__(256) void gemm_kernel(
    const float* __restrict__ x, const u16* __restrict__ S,
    const u16* __restrict__ WQ, const float* __restrict__ AB,
    float* __restrict__ out)
{
    __shared__ __align__(16) u16 sb[2][64][64];

    const int tid = threadIdx.x;
    const int b  = blockIdx.z;
    const int o0 = blockIdx.y * 128;
    const int p0 = blockIdx.x * 64;

    // fill mapping: 4 lanes per px, 16 ch each (2 granules of 8)
    const int px_s = tid >> 2;
    const int cs   = tid & 3;
    const u16* srow = S + (size_t)(b * HW_ + p0 + px_s) * 2304 + cs * 16;
    const int sw0 = (((cs * 2)     ^ (px_s & 7)) << 3);
    const int sw1 = (((cs * 2 + 1) ^ (px_s & 7)) << 3);

    const int wave = tid >> 6;
    const int lane = tid & 63;
    const int quad = lane >> 4;
    const int l15  = lane & 15;
    const int wo = (wave >> 1) * 64;
    const int wp = (wave & 1) * 32;

    float4v acc[4][2];
#pragma unroll
    for (int i = 0; i < 4; i++)
#pragma unroll
        for (int jn = 0; jn < 2; jn++)
            acc[i][jn] = float4v{0.f, 0.f, 0.f, 0.f};

    const u16* wbase = WQ + (o0 + wo + l15) * 32 + quad * 8;

    ushort8 ra0, ra1, rb0, rb1, rc0, rc1;
    short8v wreg[2][4], wnxt[2][4];

    auto load_s = [&](int ch, ushort8& r0, ushort8& r1) {
        r0 = *(const ushort8*)(srow + ch * 64);
        r1 = *(const ushort8*)(srow + ch * 64 + 8);
    };
    auto store_s = [&](int buf, const ushort8& r0, const ushort8& r1) {
        *(ushort8*)&sb[buf][px_s][sw0] = r0;
        *(ushort8*)&sb[buf][px_s][sw1] = r1;
    };
    auto load_w = [&](int ch, short8v Wv[2][4]) {
        const u16* p = wbase + (size_t)ch * 16384;
#pragma unroll
        for (int ks = 0; ks < 2; ++ks)
#pragma unroll
            for (int mt = 0; mt < 4; ++mt)
                Wv[ks][mt] = *(const short8v*)(p + ks * 8192 + mt * 512);
    };

    // prologue
    load_s(0, ra0, ra1);
    load_s(1, rb0, rb1);
    load_w(0, wreg);
    store_s(0, ra0, ra1);
    __syncthreads();

    int buf = 0;
    for (int ch = 0; ch < 36; ++ch) {
        if (ch + 2 < 36) load_s(ch + 2, rc0, rc1);
        if (ch + 1 < 36) load_w(ch + 1, wnxt);
#pragma unroll
        for (int ks = 0; ks < 2; ++ks) {
            short8v b0 = *(const short8v*)
                &sb[buf][wp + l15][((ks * 4 + quad) ^ (l15 & 7)) << 3];
            short8v b1 = *(const short8v*)
                &sb[buf][wp + 16 + l15][((ks * 4 + quad) ^ (l15 & 7)) << 3];
#pragma unroll
            for (int mt = 0; mt < 4; ++mt) {
                acc[mt][0] = __builtin_amdgcn_mfma_f32_16x16x32_bf16(
                    wreg[ks][mt], b0, acc[mt][0], 0, 0, 0);
                acc[mt][1] = __builtin_amdgcn_mfma_f32_16x16x32_bf16(
                    wreg[ks][mt], b1, acc[mt][1], 0, 0, 0);
            }
        }
        if (ch + 1 < 36) {
            store_s(buf ^ 1, rb0, rb1);
            rb0 = rc0; rb1 = rc1;
#pragma unroll
            for (int ks = 0; ks < 2; ++ks)
#pragma unroll
                for (int mt = 0; mt < 4; ++mt)
                    wreg[ks][mt] = wnxt[ks][mt];
            __syncthreads();
            buf ^= 1;
        }
    }

    // epilogue: BN fold + relu + residual
    const float* Ao = AB;
    const float* Bo = AB + 256;
#pragma unroll
    for (int mt = 0; mt < 4; mt++) {
#pragma unroll
        for (int nt = 0; nt < 2; nt++) {
            int pix = p0 + wp + nt * 16 + l15;
#pragma unroll
            for (int r = 0; r < 4; r++) {
                int o = o0 + wo + mt * 16 + quad * 4 + r;
                float v = acc[mt][nt][r] * Ao[o] + Bo[o];
                v = fmaxf(v, 0.f);
                int gi = (b * C_ + o) * HW_ + pix;
                out[gi] = x[gi] + v;
            }
        }
    }
}

extern "C" void kernel_launch(void* const* d_in, const int* in_sizes, int n_in,
                              void* d_out, int out_size, void* d_ws, size_t ws_size,
                              hipStream_t stream)
{
    (void)in_sizes; (void)n_in; (void)out_size; (void)ws_size;
    const float* x      = (const float*)d_in[0];
    const float* w_off  = (const float*)d_in[1];
    const float* b_off  = (const float*)d_in[2];
    const float* w_conv = (const float*)d_in[3];
    const float* b_conv = (const float*)d_in[4];
    const float* gamma  = (const float*)d_in[5];
    const float* beta   = (const float*)d_in[6];
    const float* rmean  = (const float*)d_in[7];
    const float* rvar   = (const float*)d_in[8];
    float* out = (float*)d_out;

    float* ws = (float*)d_ws;
    float* AB = ws;                            // 512 floats
    u16* WQ = (u16*)(AB + 512);                // 589824
    u16* WO = WQ + 589824;                     // 73728
    u16* XT = WO + 73728;                      // 4718592
    u16* S  = XT + 4718592;                    // 2*9216*2304 = 42467328

    prep_w_kernel<<<2592, 256, 0, stream>>>(w_conv, w_off, b_conv, gamma, beta,
                                            rmean, rvar, AB, WQ, WO);
    xt_kernel<<<dim3(96, 16), 256, 0, stream>>>(x, XT);
    off_lerp_kernel<<<dim3(576, 2), 256, 0, stream>>>(XT, WO, b_off, S);
    gemm_kernel<<<dim3(144, 2, 2), 256, 0, stream>>>(x, S, WQ, AB, out);
}